// Round 15
// baseline (502.679 us; speedup 1.0000x reference)
//
#include <hip/hip_runtime.h>
#include <hip/hip_bf16.h>
#include <cstdint>

typedef float f32x4 __attribute__((ext_vector_type(4)));
typedef __bf16 bf16x8 __attribute__((ext_vector_type(8)));
typedef __bf16 bf16x4 __attribute__((ext_vector_type(4)));
typedef __bf16 bf16x2 __attribute__((ext_vector_type(2)));

#define HID 128

// Fused: blocks 0..255 count dst-degrees; blocks 256..1343 pack weights.
__global__ void count_pack(const int* __restrict__ dstI, int* __restrict__ cnt, int E,
                           const float* __restrict__ Wa, const float* __restrict__ Wb,
                           const float* __restrict__ Wc,
                           __bf16* __restrict__ Ba, __bf16* __restrict__ Bb,
                           __bf16* __restrict__ Bc) {
    if (blockIdx.x < 256) {
        for (int e = blockIdx.x * 256 + threadIdx.x; e < E; e += 65536)
            atomicAdd(&cnt[dstI[e]], 1);
        return;
    }
    int idx = (blockIdx.x - 256) * 256 + threadIdx.x;
    const int T1 = 512 * 512;
    const int T2 = 28 * 512;
    const float* W; __bf16* B; int li;
    if (idx < T1)            { W = Wa; B = Ba; li = idx; }
    else if (idx < T1 + T2)  { W = Wb; B = Bb; li = idx - T1; }
    else                     { W = Wc; B = Bc; li = idx - T1 - T2; }
    int lane = li & 63;
    int nf = (li >> 6) & 7;
    int ki = li >> 9;
    int n = nf * 16 + (lane & 15);
    int kb = ki * 32 + ((lane >> 4) * 8);
    bf16x8 v;
#pragma unroll
    for (int j = 0; j < 8; ++j) v[j] = (__bf16)W[(size_t)(kb + j) * HID + n];
    *reinterpret_cast<bf16x8*>(B + (size_t)li * 8) = v;
}

// mel GEMM (K-split x4, bf16 partials) with CSR-fill blocks interleaved.
// NEW vs r14: A staged via __builtin_amdgcn_global_load_lds width=16 (fp32 tile,
// cvt->bf16 at LDS-read). No register consumer for the loads -> no forced vmcnt
// drain on the wave's critical path; loads stay outstanding through compute and
// drain inside the barrier. Swizzle moved to per-lane GLOBAL address (LDS dest
// is linear, m104/m173): src byte = (lane*16) ^ ((row&7)<<4); reads use the same
// XOR -> 2-way banks (free). K-step 256 floats, 2x32KB LDS double-buffer.
__global__ __launch_bounds__(256, 2) void gemm_mel_fill(
    const float* __restrict__ A0,
    const __bf16* __restrict__ Bf,
    __bf16* __restrict__ part,
    const int* __restrict__ srcI, const int* __restrict__ dstI,
    const int* __restrict__ offs, int* __restrict__ cnt,
    int* __restrict__ srcs, int E)
{
    const int b = blockIdx.x;
    if ((b % 11) == 10) {
        int fid = b / 11;                       // 0..249
        for (int e = fid * 256 + threadIdx.x; e < E; e += 64000) {
            int d = dstI[e];
            int p = offs[d] + atomicAdd(&cnt[d], -1) - 1;
            srcs[p] = srcI[e];
        }
        return;
    }
    const int bid = b - b / 11;                 // 0..2499
    const int tid = threadIdx.x;
    const int lane = tid & 63;
    const int wv = tid >> 6;
    const int quarter = bid / 625;
    const int row_base = (bid - quarter * 625) * 32;
    const int rif = lane & 15;
    const int kg = lane >> 4;
    const int s0 = quarter * 16;                // 16 steps of 256 floats

    __shared__ __align__(16) char ldsb[65536];  // 2 x 32KB fp32 tile; epilogue red aliases

    f32x4 zero = {0.f, 0.f, 0.f, 0.f};
    f32x4 acc[2][8];
#pragma unroll
    for (int i = 0; i < 2; ++i)
#pragma unroll
        for (int j = 0; j < 8; ++j) acc[i][j] = zero;

    const bf16x8* __restrict__ BfV = reinterpret_cast<const bf16x8*>(Bf);

    // 8 rows per wave; lane l's 16B lands at LDS row*1024 + l*16 (linear);
    // global source pre-swizzled so LDS[d] = G[d ^ ((row&7)<<4)].
    auto issue_loads = [&](int s_abs, int buf) {
#pragma unroll
        for (int j = 0; j < 8; ++j) {
            int row = wv * 8 + j;
            unsigned sw = (unsigned)((row & 7) << 4);
            const char* g = reinterpret_cast<const char*>(
                                A0 + (size_t)(row_base + row) * 16384 + (size_t)s_abs * 256)
                            + (((unsigned)(lane * 16)) ^ sw);
            __builtin_amdgcn_global_load_lds(
                (const __attribute__((address_space(1))) void*)g,
                (__attribute__((address_space(3))) void*)(ldsb + buf * 32768 + row * 1024),
                16, 0, 0);
        }
    };
    auto compute = [&](int cur, int s_abs) {
#pragma unroll
        for (int ki2 = 0; ki2 < 2; ++ki2) {
            const int ki = wv * 2 + ki2;
            bf16x8 af[2];
#pragma unroll
            for (int mi = 0; mi < 2; ++mi) {
                int row = mi * 16 + rif;
                unsigned sw = (unsigned)((row & 7) << 4);
                unsigned g0 = (unsigned)(ki * 128 + kg * 32);
                const char* base = ldsb + cur * 32768 + row * 1024;
                f32x4 lo = *reinterpret_cast<const f32x4*>(base + (g0 ^ sw));
                f32x4 hi = *reinterpret_cast<const f32x4*>(base + ((g0 + 16) ^ sw));
                af[mi][0] = (__bf16)lo.x; af[mi][1] = (__bf16)lo.y;
                af[mi][2] = (__bf16)lo.z; af[mi][3] = (__bf16)lo.w;
                af[mi][4] = (__bf16)hi.x; af[mi][5] = (__bf16)hi.y;
                af[mi][6] = (__bf16)hi.z; af[mi][7] = (__bf16)hi.w;
            }
            const bf16x8* bp = BfV + (size_t)(s_abs * 8 + ki) * 512 + lane;
#pragma unroll
            for (int nf = 0; nf < 8; ++nf) {
                bf16x8 bq = bp[nf * 64];
                acc[0][nf] = __builtin_amdgcn_mfma_f32_16x16x32_bf16(af[0], bq, acc[0][nf], 0, 0, 0);
                acc[1][nf] = __builtin_amdgcn_mfma_f32_16x16x32_bf16(af[1], bq, acc[1][nf], 0, 0, 0);
            }
        }
    };

    issue_loads(s0, 0);
    __syncthreads();                            // drains prologue loads
    for (int t = 0; t < 16; ++t) {
        int cur = t & 1;
        if (t + 1 < 16) issue_loads(s0 + t + 1, cur ^ 1);   // fire-and-forget
        compute(cur, s0 + t);                               // loads in flight throughout
        __syncthreads();                                    // drain happens here, off critical path
    }

    // epilogue: cross-wave reduction (red aliases ldsb), bf16 partials
    float* red = reinterpret_cast<float*>(ldsb);
#pragma unroll
    for (int mi = 0; mi < 2; ++mi)
#pragma unroll
        for (int nf = 0; nf < 8; ++nf)
#pragma unroll
            for (int j = 0; j < 4; ++j)
                red[(wv * 32 + mi * 16 + kg * 4 + j) * HID + nf * 16 + rif] = acc[mi][nf][j];
    __syncthreads();
    __bf16* pb = part + (size_t)quarter * 20000 * HID;
#pragma unroll
    for (int p = 0; p < 8; ++p) {
        int idx = tid + p * 256;
        int r = idx >> 6;
        int c2 = (idx & 63) * 2;
        float v0 = red[r * HID + c2]     + red[(32 + r) * HID + c2]
                 + red[(64 + r) * HID + c2] + red[(96 + r) * HID + c2];
        float v1 = red[r * HID + c2 + 1] + red[(32 + r) * HID + c2 + 1]
                 + red[(64 + r) * HID + c2 + 1] + red[(96 + r) * HID + c2 + 1];
        union { bf16x2 h; unsigned int u; } cv;
        cv.h[0] = (__bf16)v0; cv.h[1] = (__bf16)v1;
        __builtin_nontemporal_store(cv.u,
            reinterpret_cast<unsigned int*>(pb + (size_t)(row_base + r) * HID + c2));
    }
}

// Fused: m = relu(sum partials + bmel) inline; x = relu([text|m]@Wcat + bcat);
// h1s = (x @ W1) * dinv -> bf16.
__global__ __launch_bounds__(256) void gemm_cat_h1(
    const float* __restrict__ A0,
    const __bf16* __restrict__ part,
    const float* __restrict__ bmel,
    const __bf16* __restrict__ Bf2,
    const __bf16* __restrict__ Bf3,
    const float* __restrict__ bcat,
    const float* __restrict__ dinv,
    __bf16* __restrict__ h1)
{
    const int tid = threadIdx.x;
    const int lane = tid & 63;
    const int w = tid >> 6;
    const int row_base = blockIdx.x * 32;
    const int rif = lane & 15;
    const int kg = lane >> 4;

    f32x4 zero = {0.f, 0.f, 0.f, 0.f};
    f32x4 acc[2][8];
#pragma unroll
    for (int i = 0; i < 2; ++i)
#pragma unroll
        for (int j = 0; j < 8; ++j) acc[i][j] = zero;

    const bf16x8* __restrict__ Bf2V = reinterpret_cast<const bf16x8*>(Bf2);
    const int kstart = w * 224;
    const size_t N = (size_t)20000 * HID;

#pragma unroll
    for (int it = 0; it < 7; ++it) {
        const int k0 = kstart + it * 32;
        const int kc = k0 + kg * 8;
        bf16x8 af[2];
#pragma unroll
        for (int mi = 0; mi < 2; ++mi) {
            const int row = row_base + mi * 16 + rif;
            if (k0 < 768) {
                const f32x4* apv = reinterpret_cast<const f32x4*>(A0 + (size_t)row * 768 + kc);
                f32x4 v0 = __builtin_nontemporal_load(apv);
                f32x4 v1 = __builtin_nontemporal_load(apv + 1);
                af[mi][0] = (__bf16)v0.x; af[mi][1] = (__bf16)v0.y;
                af[mi][2] = (__bf16)v0.z; af[mi][3] = (__bf16)v0.w;
                af[mi][4] = (__bf16)v1.x; af[mi][5] = (__bf16)v1.y;
                af[mi][6] = (__bf16)v1.z; af[mi][7] = (__bf16)v1.w;
            } else {
                const int mcol = kc - 768;
                const size_t base = (size_t)row * HID + mcol;
                bf16x8 q0 = *reinterpret_cast<const bf16x8*>(part + base);
                bf16x8 q1 = *reinterpret_cast<const bf16x8*>(part + N + base);
                bf16x8 q2 = *reinterpret_cast<const bf16x8*>(part + 2 * N + base);
                bf16x8 q3 = *reinterpret_cast<const bf16x8*>(part + 3 * N + base);
                const float* bp_ = bmel + mcol;
#pragma unroll
                for (int jj = 0; jj < 8; ++jj) {
                    float v = (float)q0[jj] + (float)q1[jj] + (float)q2[jj] + (float)q3[jj] + bp_[jj];
                    af[mi][jj] = (__bf16)fmaxf(v, 0.f);
                }
            }
        }
        const bf16x8* bp = Bf2V + (size_t)(k0 >> 5) * 512 + lane;
#pragma unroll
        for (int nf = 0; nf < 8; ++nf) {
            bf16x8 bq = bp[nf * 64];
            acc[0][nf] = __builtin_amdgcn_mfma_f32_16x16x32_bf16(af[0], bq, acc[0][nf], 0, 0, 0);
            acc[1][nf] = __builtin_amdgcn_mfma_f32_16x16x32_bf16(af[1], bq, acc[1][nf], 0, 0, 0);
        }
    }

    __shared__ float red[4][32][HID];
    __shared__ __bf16 xs[32][136];

#pragma unroll
    for (int mi = 0; mi < 2; ++mi)
#pragma unroll
        for (int nf = 0; nf < 8; ++nf)
#pragma unroll
            for (int j = 0; j < 4; ++j)
                red[w][mi * 16 + kg * 4 + j][nf * 16 + rif] = acc[mi][nf][j];
    __syncthreads();
#pragma unroll
    for (int p = 0; p < 16; ++p) {
        int idx = tid + p * 256;
        int r = idx >> 7, c = idx & 127;
        float v = red[0][r][c] + red[1][r][c] + red[2][r][c] + red[3][r][c];
        v = fmaxf(v + bcat[c], 0.f);
        xs[r][c] = (__bf16)v;
    }
    __syncthreads();

    f32x4 acc2[2][8];
#pragma unroll
    for (int i = 0; i < 2; ++i)
#pragma unroll
        for (int j = 0; j < 8; ++j) acc2[i][j] = zero;

    {
        const int k0 = w * 32;
        bf16x8 af[2];
#pragma unroll
        for (int mi = 0; mi < 2; ++mi)
            af[mi] = *reinterpret_cast<const bf16x8*>(&xs[mi * 16 + rif][k0 + kg * 8]);
        const bf16x8* bp = reinterpret_cast<const bf16x8*>(Bf3) + (size_t)w * 512 + lane;
#pragma unroll
        for (int nf = 0; nf < 8; ++nf) {
            bf16x8 bq = bp[nf * 64];
            acc2[0][nf] = __builtin_amdgcn_mfma_f32_16x16x32_bf16(af[0], bq, acc2[0][nf], 0, 0, 0);
            acc2[1][nf] = __builtin_amdgcn_mfma_f32_16x16x32_bf16(af[1], bq, acc2[1][nf], 0, 0, 0);
        }
    }

#pragma unroll
    for (int mi = 0; mi < 2; ++mi)
#pragma unroll
        for (int nf = 0; nf < 8; ++nf)
#pragma unroll
            for (int j = 0; j < 4; ++j)
                red[w][mi * 16 + kg * 4 + j][nf * 16 + rif] = acc2[mi][nf][j];
    __syncthreads();
#pragma unroll
    for (int p = 0; p < 16; ++p) {
        int idx = tid + p * 256;
        int r = idx >> 7, c = idx & 127;
        float v = red[0][r][c] + red[1][r][c] + red[2][r][c] + red[3][r][c];
        h1[(size_t)(row_base + r) * HID + c] = (__bf16)(v * dinv[row_base + r]);
    }
}

// scan: offs exclusive, offs[n]=E; dinv = rsqrt(deg+1)
__global__ __launch_bounds__(1024) void scan_block(const int* __restrict__ cnt,
    int* __restrict__ offs, float* __restrict__ dinv, int n) {
    int tid = threadIdx.x;
    int CH = (n + 1023) >> 10;
    int s0 = tid * CH;
    int s1 = min(s0 + CH, n);
    int sum = 0;
    for (int i = s0; i < s1; ++i) sum += cnt[i];
    int lane = tid & 63, wv = tid >> 6;
    int s = sum;
#pragma unroll
    for (int off = 1; off < 64; off <<= 1) {
        int t = __shfl_up(s, off);
        if (lane >= off) s += t;
    }
    __shared__ int wsum[16];
    __shared__ int wbase[16];
    if (lane == 63) wsum[wv] = s;
    __syncthreads();
    if (tid == 0) {
        int a = 0;
#pragma unroll
        for (int k = 0; k < 16; ++k) { wbase[k] = a; a += wsum[k]; }
        offs[n] = a;
    }
    __syncthreads();
    int run = wbase[wv] + (s - sum);
    for (int i = s0; i < s1; ++i) {
        int v = cnt[i];
        offs[i] = run;
        dinv[i] = rsqrtf((float)(v + 1));
        run += v;
    }
}

// h1s pre-scaled. yb = relu((h1s[i]+sum_s h1s[s])*di + b1); h2s = (yb@W2)*di.
__global__ __launch_bounds__(64) void agg_h_w2(const __bf16* __restrict__ hs,
    const float* __restrict__ dinv, const int* __restrict__ offs,
    const int* __restrict__ srcs,
    const float* __restrict__ b1, const float* __restrict__ W2,
    float* __restrict__ h2, int n) {
    int i = blockIdx.x;
    int c = threadIdx.x;
    float di = dinv[i];
    const int col = 2 * c;
    bf16x2 hv = *reinterpret_cast<const bf16x2*>(hs + (size_t)i * HID + col);
    float a0 = (float)hv[0];
    float a1 = (float)hv[1];
    int o = offs[i];
    int e = offs[i + 1] - o;
    int t = 0;
    for (; t + 8 <= e; t += 8) {
        int sx[8];
#pragma unroll
        for (int q = 0; q < 8; ++q) sx[q] = srcs[o + t + q];
        bf16x2 v[8];
#pragma unroll
        for (int q = 0; q < 8; ++q) v[q] = *reinterpret_cast<const bf16x2*>(hs + (size_t)sx[q] * HID + col);
#pragma unroll
        for (int q = 0; q < 8; ++q) { a0 += (float)v[q][0]; a1 += (float)v[q][1]; }
    }
    for (; t < e; ++t) {
        int s = srcs[o + t];
        bf16x2 v = *reinterpret_cast<const bf16x2*>(hs + (size_t)s * HID + col);
        a0 += (float)v[0];
        a1 += (float)v[1];
    }
    float yb0 = fmaxf(a0 * di + b1[col], 0.f);
    float yb1 = fmaxf(a1 * di + b1[col + 1], 0.f);
    float4 w0 = *reinterpret_cast<const float4*>(W2 + col * 4);
    float4 w1 = *reinterpret_cast<const float4*>(W2 + col * 4 + 4);
    float p0 = yb0 * w0.x + yb1 * w1.x;
    float p1 = yb0 * w0.y + yb1 * w1.y;
    float p2 = yb0 * w0.z + yb1 * w1.z;
    float p3 = yb0 * w0.w + yb1 * w1.w;
#pragma unroll
    for (int off = 32; off; off >>= 1) {
        p0 += __shfl_down(p0, off);
        p1 += __shfl_down(p1, off);
        p2 += __shfl_down(p2, off);
        p3 += __shfl_down(p3, off);
    }
    if (c == 0) {
        float4 r = {p0 * di, p1 * di, p2 * di, p3 * di};
        *reinterpret_cast<float4*>(h2 + (size_t)i * 4) = r;
    }
}

// out = (h2s[i] + sum_s h2s[s]) * di + b2
__global__ void agg4(const float* __restrict__ h2s, const float* __restrict__ dinv,
                     const int* __restrict__ offs,
                     const int* __restrict__ srcs, const float* __restrict__ b2,
                     float* __restrict__ out, int n) {
    int gid = blockIdx.x * 256 + threadIdx.x;
    int i = gid >> 2;
    int c = gid & 3;
    if (i >= n) return;
    float di = dinv[i];
    float acc = h2s[(size_t)i * 4 + c];
    int o = offs[i];
    int e = offs[i + 1] - o;
    int t = 0;
    for (; t + 4 <= e; t += 4) {
        int a0 = srcs[o + t], a1 = srcs[o + t + 1], a2 = srcs[o + t + 2], a3 = srcs[o + t + 3];
        acc += h2s[(size_t)a0 * 4 + c] + h2s[(size_t)a1 * 4 + c]
             + h2s[(size_t)a2 * 4 + c] + h2s[(size_t)a3 * 4 + c];
    }
    for (; t < e; ++t) {
        int s = srcs[o + t];
        acc += h2s[(size_t)s * 4 + c];
    }
    out[(size_t)i * 4 + c] = acc * di + b2[c];
}

extern "C" void kernel_launch(void* const* d_in, const int* in_sizes, int n_in,
                              void* d_out, int out_size, void* d_ws, size_t ws_size,
                              hipStream_t stream) {
    const float* text = (const float*)d_in[0];
    const float* mel  = (const float*)d_in[1];
    const int*   ei   = (const int*)d_in[2];
    const float* Wmel = (const float*)d_in[3];
    const float* bmel = (const float*)d_in[4];
    const float* Wcat = (const float*)d_in[5];
    const float* bcat = (const float*)d_in[6];
    const float* W1   = (const float*)d_in[7];
    const float* b1   = (const float*)d_in[8];
    const float* W2   = (const float*)d_in[9];
    const float* b2   = (const float*)d_in[10];
    float* out = (float*)d_out;

    const int n = in_sizes[0] / 768;   // 20000
    const int E = in_sizes[2] / 2;     // 640000
    const int Kmel = 16384;

    char* ws = (char*)d_ws;
    size_t off = 0;
    auto alloc = [&](size_t bytes) {
        void* p = ws + off;
        off += (bytes + 255) & ~(size_t)255;
        return p;
    };
    __bf16* Bf1 = (__bf16*)alloc((size_t)Kmel * HID * 2);
    __bf16* Bf2 = (__bf16*)alloc((size_t)896 * HID * 2);
    __bf16* Bf3 = (__bf16*)alloc((size_t)HID * HID * 2);
    __bf16* part = (__bf16*)alloc((size_t)4 * n * HID * 2);
    __bf16* h1  = (__bf16*)alloc((size_t)n * HID * 2);
    float* h2   = (float*)alloc((size_t)n * 4 * 4);
    int* cnt    = (int*)alloc((size_t)n * 4);
    int* offs   = (int*)alloc((size_t)(n + 1) * 4);
    float* dinv = (float*)alloc((size_t)n * 4);
    int* srcs   = (int*)alloc((size_t)E * 4);
    (void)ws_size; (void)n_in; (void)out_size;

    const int* srcI = ei;
    const int* dstI = ei + E;

    // degrees + weight pack (fused)
    (void)hipMemsetAsync(cnt, 0, n * 4, stream);
    count_pack<<<1344, 256, 0, stream>>>(dstI, cnt, E, Wmel, Wcat, W1, Bf1, Bf2, Bf3);
    // prefix sums + dinv
    scan_block<<<1, 1024, 0, stream>>>(cnt, offs, dinv, n);
    // mel GEMM (global_load_lds staging) with CSR-fill interleaved
    gemm_mel_fill<<<2750, 256, 0, stream>>>(mel, Bf1, part, srcI, dstI, offs, cnt, srcs, E);
    // fused combine+cat: x = relu([text|relu(sum parts+bmel)]@Wcat+bcat); h1s=(x@W1)*dinv
    gemm_cat_h1<<<n / 32, 256, 0, stream>>>(text, part, bmel, Bf2, Bf3, bcat, dinv, h1);
    // h2s = relu(agg(h1s)+b1) @ W2 * dinv
    agg_h_w2<<<n, 64, 0, stream>>>(h1, dinv, offs, srcs, b1, W2, h2, n);
    // out = agg(h2s) + b2
    agg4<<<(n * 4 + 255) / 256, 256, 0, stream>>>(h2, dinv, offs, srcs, b2, out, n);
}

// Round 16
// 420.838 us; speedup vs baseline: 1.1945x; 1.1945x over previous
//
#include <hip/hip_runtime.h>
#include <hip/hip_bf16.h>
#include <cstdint>

typedef float f32x4 __attribute__((ext_vector_type(4)));
typedef __bf16 bf16x8 __attribute__((ext_vector_type(8)));
typedef __bf16 bf16x4 __attribute__((ext_vector_type(4)));
typedef __bf16 bf16x2 __attribute__((ext_vector_type(2)));

#define HID 128

// Fused: blocks 0..255 count dst-degrees (grid-stride); blocks 256..1343 pack
// Wmel/Wcat/W1 fp32 -> fragment-major bf16. Independent work, one launch.
__global__ void count_pack(const int* __restrict__ dstI, int* __restrict__ cnt, int E,
                           const float* __restrict__ Wa, const float* __restrict__ Wb,
                           const float* __restrict__ Wc,
                           __bf16* __restrict__ Ba, __bf16* __restrict__ Bb,
                           __bf16* __restrict__ Bc) {
    if (blockIdx.x < 256) {
        for (int e = blockIdx.x * 256 + threadIdx.x; e < E; e += 65536)
            atomicAdd(&cnt[dstI[e]], 1);
        return;
    }
    int idx = (blockIdx.x - 256) * 256 + threadIdx.x;   // 0..278527 exactly
    const int T1 = 512 * 512;
    const int T2 = 28 * 512;
    const float* W; __bf16* B; int li;
    if (idx < T1)            { W = Wa; B = Ba; li = idx; }
    else if (idx < T1 + T2)  { W = Wb; B = Bb; li = idx - T1; }
    else                     { W = Wc; B = Bc; li = idx - T1 - T2; }
    int lane = li & 63;
    int nf = (li >> 6) & 7;
    int ki = li >> 9;
    int n = nf * 16 + (lane & 15);
    int kb = ki * 32 + ((lane >> 4) * 8);
    bf16x8 v;
#pragma unroll
    for (int j = 0; j < 8; ++j) v[j] = (__bf16)W[(size_t)(kb + j) * HID + n];
    *reinterpret_cast<bf16x8*>(B + (size_t)li * 8) = v;
}

// mel GEMM (K-split x4, bf16 partials) with CSR-fill blocks interleaved:
// every 11th block (b%11==10, 250 total) does a short grid-stride fill pass
// then exits, returning its slot to mel. Fill hides inside mel's HBM-bound run.
// r4-lineage reg-staged inner loop: best of 7 staging variants tested (r4..r15).
__global__ __launch_bounds__(256, 2) void gemm_mel_fill(
    const float* __restrict__ A0,
    const __bf16* __restrict__ Bf,
    __bf16* __restrict__ part,
    const int* __restrict__ srcI, const int* __restrict__ dstI,
    const int* __restrict__ offs, int* __restrict__ cnt,
    int* __restrict__ srcs, int E)
{
    const int b = blockIdx.x;
    if ((b % 11) == 10) {
        int fid = b / 11;                       // 0..249
        for (int e = fid * 256 + threadIdx.x; e < E; e += 64000) {
            int d = dstI[e];
            int p = offs[d] + atomicAdd(&cnt[d], -1) - 1;
            srcs[p] = srcI[e];
        }
        return;
    }
    const int bid = b - b / 11;                 // 0..2499 (mel tile index)
    const int tid = threadIdx.x;
    const int lane = tid & 63;
    const int wv = tid >> 6;
    const int quarter = bid / 625;
    const int row_base = (bid - quarter * 625) * 32;
    const int rif = lane & 15;
    const int kg = lane >> 4;
    const int s0 = quarter * 8;

    __shared__ __align__(16) char ldsb[65536];

    f32x4 zero = {0.f, 0.f, 0.f, 0.f};
    f32x4 acc[2][8];
#pragma unroll
    for (int i = 0; i < 2; ++i)
#pragma unroll
        for (int j = 0; j < 8; ++j) acc[i][j] = zero;

    const bf16x8* __restrict__ BfV = reinterpret_cast<const bf16x8*>(Bf);

    f32x4 st[16];

    auto stage_load = [&](int s) {
#pragma unroll
        for (int j = 0; j < 16; ++j) {
            int seg = wv * 16 + j;
            int row = seg >> 1, halfseg = seg & 1;
            const float* gp = A0 + (size_t)(row_base + row) * 16384 + s * 512 + halfseg * 256 + (lane << 2);
            st[j] = __builtin_nontemporal_load(reinterpret_cast<const f32x4*>(gp));
        }
    };
    auto stage_write = [&](int buf) {
#pragma unroll
        for (int j = 0; j < 16; ++j) {
            int seg = wv * 16 + j;
            int row = seg >> 1, halfseg = seg & 1;
            int byte = row * 1024 + ((halfseg * 512 + lane * 8) ^ ((row & 7) << 4)) + buf * 32768;
            bf16x4 v;
            v[0] = (__bf16)st[j][0]; v[1] = (__bf16)st[j][1];
            v[2] = (__bf16)st[j][2]; v[3] = (__bf16)st[j][3];
            *reinterpret_cast<bf16x4*>(ldsb + byte) = v;
        }
    };
    auto compute2 = [&](int cur, int s, int kt0) {
#pragma unroll
        for (int kt = kt0; kt < kt0 + 2; ++kt) {
            bf16x8 af[2];
#pragma unroll
            for (int mi = 0; mi < 2; ++mi) {
                int row = mi * 16 + rif;
                int byte = row * 1024 + ((wv * 256 + kt * 64 + kg * 16) ^ ((rif & 7) << 4)) + cur * 32768;
                af[mi] = *reinterpret_cast<const bf16x8*>(ldsb + byte);
            }
            int ki = s * 16 + wv * 4 + kt;
            const bf16x8* bp = BfV + (size_t)ki * 512 + lane;
#pragma unroll
            for (int nf = 0; nf < 8; ++nf) {
                bf16x8 bq = bp[nf * 64];
                acc[0][nf] = __builtin_amdgcn_mfma_f32_16x16x32_bf16(af[0], bq, acc[0][nf], 0, 0, 0);
                acc[1][nf] = __builtin_amdgcn_mfma_f32_16x16x32_bf16(af[1], bq, acc[1][nf], 0, 0, 0);
            }
        }
    };

    stage_load(s0);
    stage_write(0);
    for (int t = 0; t < 8; ++t) {
        int s = s0 + t;
        int cur = t & 1;
        if (t + 1 < 8) stage_load(s + 1);
        __syncthreads();
        compute2(cur, s, 0);
        compute2(cur, s, 2);
        if (t + 1 < 8) stage_write(cur ^ 1);
    }

    __syncthreads();
    float* red = reinterpret_cast<float*>(ldsb);
#pragma unroll
    for (int mi = 0; mi < 2; ++mi)
#pragma unroll
        for (int nf = 0; nf < 8; ++nf)
#pragma unroll
            for (int j = 0; j < 4; ++j)
                red[(wv * 32 + mi * 16 + kg * 4 + j) * HID + nf * 16 + rif] = acc[mi][nf][j];
    __syncthreads();
    __bf16* pb = part + (size_t)quarter * 20000 * HID;
#pragma unroll
    for (int p = 0; p < 8; ++p) {
        int idx = tid + p * 256;
        int r = idx >> 6;
        int c2 = (idx & 63) * 2;
        float v0 = red[r * HID + c2]     + red[(32 + r) * HID + c2]
                 + red[(64 + r) * HID + c2] + red[(96 + r) * HID + c2];
        float v1 = red[r * HID + c2 + 1] + red[(32 + r) * HID + c2 + 1]
                 + red[(64 + r) * HID + c2 + 1] + red[(96 + r) * HID + c2 + 1];
        union { bf16x2 h; unsigned int u; } cv;
        cv.h[0] = (__bf16)v0; cv.h[1] = (__bf16)v1;
        __builtin_nontemporal_store(cv.u,
            reinterpret_cast<unsigned int*>(pb + (size_t)(row_base + r) * HID + c2));
    }
}

// Fused: m = relu(sum partials + bmel) inline; x = relu([text|m]@Wcat + bcat);
// h1s = (x @ W1) * dinv -> bf16.
__global__ __launch_bounds__(256) void gemm_cat_h1(
    const float* __restrict__ A0,
    const __bf16* __restrict__ part,
    const float* __restrict__ bmel,
    const __bf16* __restrict__ Bf2,
    const __bf16* __restrict__ Bf3,
    const float* __restrict__ bcat,
    const float* __restrict__ dinv,
    __bf16* __restrict__ h1)
{
    const int tid = threadIdx.x;
    const int lane = tid & 63;
    const int w = tid >> 6;
    const int row_base = blockIdx.x * 32;
    const int rif = lane & 15;
    const int kg = lane >> 4;

    f32x4 zero = {0.f, 0.f, 0.f, 0.f};
    f32x4 acc[2][8];
#pragma unroll
    for (int i = 0; i < 2; ++i)
#pragma unroll
        for (int j = 0; j < 8; ++j) acc[i][j] = zero;

    const bf16x8* __restrict__ Bf2V = reinterpret_cast<const bf16x8*>(Bf2);
    const int kstart = w * 224;
    const size_t N = (size_t)20000 * HID;

#pragma unroll
    for (int it = 0; it < 7; ++it) {
        const int k0 = kstart + it * 32;
        const int kc = k0 + kg * 8;
        bf16x8 af[2];
#pragma unroll
        for (int mi = 0; mi < 2; ++mi) {
            const int row = row_base + mi * 16 + rif;
            if (k0 < 768) {
                const f32x4* apv = reinterpret_cast<const f32x4*>(A0 + (size_t)row * 768 + kc);
                f32x4 v0 = __builtin_nontemporal_load(apv);
                f32x4 v1 = __builtin_nontemporal_load(apv + 1);
                af[mi][0] = (__bf16)v0.x; af[mi][1] = (__bf16)v0.y;
                af[mi][2] = (__bf16)v0.z; af[mi][3] = (__bf16)v0.w;
                af[mi][4] = (__bf16)v1.x; af[mi][5] = (__bf16)v1.y;
                af[mi][6] = (__bf16)v1.z; af[mi][7] = (__bf16)v1.w;
            } else {
                const int mcol = kc - 768;
                const size_t base = (size_t)row * HID + mcol;
                bf16x8 q0 = *reinterpret_cast<const bf16x8*>(part + base);
                bf16x8 q1 = *reinterpret_cast<const bf16x8*>(part + N + base);
                bf16x8 q2 = *reinterpret_cast<const bf16x8*>(part + 2 * N + base);
                bf16x8 q3 = *reinterpret_cast<const bf16x8*>(part + 3 * N + base);
                const float* bp_ = bmel + mcol;
#pragma unroll
                for (int jj = 0; jj < 8; ++jj) {
                    float v = (float)q0[jj] + (float)q1[jj] + (float)q2[jj] + (float)q3[jj] + bp_[jj];
                    af[mi][jj] = (__bf16)fmaxf(v, 0.f);
                }
            }
        }
        const bf16x8* bp = Bf2V + (size_t)(k0 >> 5) * 512 + lane;
#pragma unroll
        for (int nf = 0; nf < 8; ++nf) {
            bf16x8 bq = bp[nf * 64];
            acc[0][nf] = __builtin_amdgcn_mfma_f32_16x16x32_bf16(af[0], bq, acc[0][nf], 0, 0, 0);
            acc[1][nf] = __builtin_amdgcn_mfma_f32_16x16x32_bf16(af[1], bq, acc[1][nf], 0, 0, 0);
        }
    }

    __shared__ float red[4][32][HID];
    __shared__ __bf16 xs[32][136];

#pragma unroll
    for (int mi = 0; mi < 2; ++mi)
#pragma unroll
        for (int nf = 0; nf < 8; ++nf)
#pragma unroll
            for (int j = 0; j < 4; ++j)
                red[w][mi * 16 + kg * 4 + j][nf * 16 + rif] = acc[mi][nf][j];
    __syncthreads();
#pragma unroll
    for (int p = 0; p < 16; ++p) {
        int idx = tid + p * 256;
        int r = idx >> 7, c = idx & 127;
        float v = red[0][r][c] + red[1][r][c] + red[2][r][c] + red[3][r][c];
        v = fmaxf(v + bcat[c], 0.f);
        xs[r][c] = (__bf16)v;
    }
    __syncthreads();

    f32x4 acc2[2][8];
#pragma unroll
    for (int i = 0; i < 2; ++i)
#pragma unroll
        for (int j = 0; j < 8; ++j) acc2[i][j] = zero;

    {
        const int k0 = w * 32;
        bf16x8 af[2];
#pragma unroll
        for (int mi = 0; mi < 2; ++mi)
            af[mi] = *reinterpret_cast<const bf16x8*>(&xs[mi * 16 + rif][k0 + kg * 8]);
        const bf16x8* bp = reinterpret_cast<const bf16x8*>(Bf3) + (size_t)w * 512 + lane;
#pragma unroll
        for (int nf = 0; nf < 8; ++nf) {
            bf16x8 bq = bp[nf * 64];
            acc2[0][nf] = __builtin_amdgcn_mfma_f32_16x16x32_bf16(af[0], bq, acc2[0][nf], 0, 0, 0);
            acc2[1][nf] = __builtin_amdgcn_mfma_f32_16x16x32_bf16(af[1], bq, acc2[1][nf], 0, 0, 0);
        }
    }

#pragma unroll
    for (int mi = 0; mi < 2; ++mi)
#pragma unroll
        for (int nf = 0; nf < 8; ++nf)
#pragma unroll
            for (int j = 0; j < 4; ++j)
                red[w][mi * 16 + kg * 4 + j][nf * 16 + rif] = acc2[mi][nf][j];
    __syncthreads();
#pragma unroll
    for (int p = 0; p < 16; ++p) {
        int idx = tid + p * 256;
        int r = idx >> 7, c = idx & 127;
        float v = red[0][r][c] + red[1][r][c] + red[2][r][c] + red[3][r][c];
        h1[(size_t)(row_base + r) * HID + c] = (__bf16)(v * dinv[row_base + r]);
    }
}

// scan: offs exclusive, offs[n]=E; dinv = rsqrt(deg+1)
__global__ __launch_bounds__(1024) void scan_block(const int* __restrict__ cnt,
    int* __restrict__ offs, float* __restrict__ dinv, int n) {
    int tid = threadIdx.x;
    int CH = (n + 1023) >> 10;
    int s0 = tid * CH;
    int s1 = min(s0 + CH, n);
    int sum = 0;
    for (int i = s0; i < s1; ++i) sum += cnt[i];
    int lane = tid & 63, wv = tid >> 6;
    int s = sum;
#pragma unroll
    for (int off = 1; off < 64; off <<= 1) {
        int t = __shfl_up(s, off);
        if (lane >= off) s += t;
    }
    __shared__ int wsum[16];
    __shared__ int wbase[16];
    if (lane == 63) wsum[wv] = s;
    __syncthreads();
    if (tid == 0) {
        int a = 0;
#pragma unroll
        for (int k = 0; k < 16; ++k) { wbase[k] = a; a += wsum[k]; }
        offs[n] = a;
    }
    __syncthreads();
    int run = wbase[wv] + (s - sum);
    for (int i = s0; i < s1; ++i) {
        int v = cnt[i];
        offs[i] = run;
        dinv[i] = rsqrtf((float)(v + 1));
        run += v;
    }
}

// h1s pre-scaled. yb = relu((h1s[i]+sum_s h1s[s])*di + b1); h2s = (yb@W2)*di.
__global__ __launch_bounds__(64) void agg_h_w2(const __bf16* __restrict__ hs,
    const float* __restrict__ dinv, const int* __restrict__ offs,
    const int* __restrict__ srcs,
    const float* __restrict__ b1, const float* __restrict__ W2,
    float* __restrict__ h2, int n) {
    int i = blockIdx.x;
    int c = threadIdx.x;
    float di = dinv[i];
    const int col = 2 * c;
    bf16x2 hv = *reinterpret_cast<const bf16x2*>(hs + (size_t)i * HID + col);
    float a0 = (float)hv[0];
    float a1 = (float)hv[1];
    int o = offs[i];
    int e = offs[i + 1] - o;
    int t = 0;
    for (; t + 8 <= e; t += 8) {
        int sx[8];
#pragma unroll
        for (int q = 0; q < 8; ++q) sx[q] = srcs[o + t + q];
        bf16x2 v[8];
#pragma unroll
        for (int q = 0; q < 8; ++q) v[q] = *reinterpret_cast<const bf16x2*>(hs + (size_t)sx[q] * HID + col);
#pragma unroll
        for (int q = 0; q < 8; ++q) { a0 += (float)v[q][0]; a1 += (float)v[q][1]; }
    }
    for (; t < e; ++t) {
        int s = srcs[o + t];
        bf16x2 v = *reinterpret_cast<const bf16x2*>(hs + (size_t)s * HID + col);
        a0 += (float)v[0];
        a1 += (float)v[1];
    }
    float yb0 = fmaxf(a0 * di + b1[col], 0.f);
    float yb1 = fmaxf(a1 * di + b1[col + 1], 0.f);
    float4 w0 = *reinterpret_cast<const float4*>(W2 + col * 4);
    float4 w1 = *reinterpret_cast<const float4*>(W2 + col * 4 + 4);
    float p0 = yb0 * w0.x + yb1 * w1.x;
    float p1 = yb0 * w0.y + yb1 * w1.y;
    float p2 = yb0 * w0.z + yb1 * w1.z;
    float p3 = yb0 * w0.w + yb1 * w1.w;
#pragma unroll
    for (int off = 32; off; off >>= 1) {
        p0 += __shfl_down(p0, off);
        p1 += __shfl_down(p1, off);
        p2 += __shfl_down(p2, off);
        p3 += __shfl_down(p3, off);
    }
    if (c == 0) {
        float4 r = {p0 * di, p1 * di, p2 * di, p3 * di};
        *reinterpret_cast<float4*>(h2 + (size_t)i * 4) = r;
    }
}

// out = (h2s[i] + sum_s h2s[s]) * di + b2
__global__ void agg4(const float* __restrict__ h2s, const float* __restrict__ dinv,
                     const int* __restrict__ offs,
                     const int* __restrict__ srcs, const float* __restrict__ b2,
                     float* __restrict__ out, int n) {
    int gid = blockIdx.x * 256 + threadIdx.x;
    int i = gid >> 2;
    int c = gid & 3;
    if (i >= n) return;
    float di = dinv[i];
    float acc = h2s[(size_t)i * 4 + c];
    int o = offs[i];
    int e = offs[i + 1] - o;
    int t = 0;
    for (; t + 4 <= e; t += 4) {
        int a0 = srcs[o + t], a1 = srcs[o + t + 1], a2 = srcs[o + t + 2], a3 = srcs[o + t + 3];
        acc += h2s[(size_t)a0 * 4 + c] + h2s[(size_t)a1 * 4 + c]
             + h2s[(size_t)a2 * 4 + c] + h2s[(size_t)a3 * 4 + c];
    }
    for (; t < e; ++t) {
        int s = srcs[o + t];
        acc += h2s[(size_t)s * 4 + c];
    }
    out[(size_t)i * 4 + c] = acc * di + b2[c];
}

extern "C" void kernel_launch(void* const* d_in, const int* in_sizes, int n_in,
                              void* d_out, int out_size, void* d_ws, size_t ws_size,
                              hipStream_t stream) {
    const float* text = (const float*)d_in[0];
    const float* mel  = (const float*)d_in[1];
    const int*   ei   = (const int*)d_in[2];
    const float* Wmel = (const float*)d_in[3];
    const float* bmel = (const float*)d_in[4];
    const float* Wcat = (const float*)d_in[5];
    const float* bcat = (const float*)d_in[6];
    const float* W1   = (const float*)d_in[7];
    const float* b1   = (const float*)d_in[8];
    const float* W2   = (const float*)d_in[9];
    const float* b2   = (const float*)d_in[10];
    float* out = (float*)d_out;

    const int n = in_sizes[0] / 768;   // 20000
    const int E = in_sizes[2] / 2;     // 640000
    const int Kmel = 16384;

    char* ws = (char*)d_ws;
    size_t off = 0;
    auto alloc = [&](size_t bytes) {
        void* p = ws + off;
        off += (bytes + 255) & ~(size_t)255;
        return p;
    };
    __bf16* Bf1 = (__bf16*)alloc((size_t)Kmel * HID * 2);
    __bf16* Bf2 = (__bf16*)alloc((size_t)896 * HID * 2);
    __bf16* Bf3 = (__bf16*)alloc((size_t)HID * HID * 2);
    __bf16* part = (__bf16*)alloc((size_t)4 * n * HID * 2);
    __bf16* h1  = (__bf16*)alloc((size_t)n * HID * 2);
    float* h2   = (float*)alloc((size_t)n * 4 * 4);
    int* cnt    = (int*)alloc((size_t)n * 4);
    int* offs   = (int*)alloc((size_t)(n + 1) * 4);
    float* dinv = (float*)alloc((size_t)n * 4);
    int* srcs   = (int*)alloc((size_t)E * 4);
    (void)ws_size; (void)n_in; (void)out_size;

    const int* srcI = ei;
    const int* dstI = ei + E;

    // degrees + weight pack (fused, one launch)
    (void)hipMemsetAsync(cnt, 0, n * 4, stream);
    count_pack<<<1344, 256, 0, stream>>>(dstI, cnt, E, Wmel, Wcat, W1, Bf1, Bf2, Bf3);
    // prefix sums + dinv
    scan_block<<<1, 1024, 0, stream>>>(cnt, offs, dinv, n);
    // mel GEMM with CSR-fill blocks interleaved (fill hides in mel's HBM-bound run)
    gemm_mel_fill<<<2750, 256, 0, stream>>>(mel, Bf1, part, srcI, dstI, offs, cnt, srcs, E);
    // fused combine+cat: x = relu([text|relu(sum parts+bmel)]@Wcat+bcat); h1s=(x@W1)*dinv
    gemm_cat_h1<<<n / 32, 256, 0, stream>>>(text, part, bmel, Bf2, Bf3, bcat, dinv, h1);
    // h2s = relu(agg(h1s)+b1) @ W2 * dinv
    agg_h_w2<<<n, 64, 0, stream>>>(h1, dinv, offs, srcs, b1, W2, h2, n);
    // out = agg(h2s) + b2
    agg4<<<(n * 4 + 255) / 256, 256, 0, stream>>>(h2, dinv, offs, srcs, b2, out, n);
}